// Round 1
// baseline (339.632 us; speedup 1.0000x reference)
//
#include <hip/hip_runtime.h>
#include <math.h>

// ---------------------------------------------------------------------------
// GCNEncoder: 3 stacked GCNConv layers (symmetric norm, self-loops) + ReLU.
// Strategy:
//   - auto-detect edge_index dtype (int64 vs int32) on device, normalize to
//     int32 src[]/dst[] arrays in ws.
//   - build dst-CSR per call: histogram -> 2-level exclusive scan -> fill.
//   - per layer: dense transform h = relu?(x) @ W (W in LDS, 4 rows/thread,
//     float4 x loads), then gather-aggregate per dst node:
//       out[d] = b + dinv[d] * ( dinv[d]*h[d] + sum_{e in(d)} dinv[src]*h[src] )
//     (one node per wave for F=64; lane = feature -> coalesced 256B gathers)
// ---------------------------------------------------------------------------

#define FULL_GRID 2048

__global__ __launch_bounds__(256) void k_detect(const unsigned int* __restrict__ words,
                                                int* __restrict__ flag) {
  // If edges are int64 (values < 2^31), every odd 32-bit word is 0.
  __shared__ int sm[256];
  int cnt = 0;
  #pragma unroll
  for (int j = 0; j < 8; ++j) {
    int idx = (threadIdx.x * 8 + j) * 2 + 1;  // odd words, first 4096 words
    cnt += (words[idx] == 0u) ? 1 : 0;
  }
  sm[threadIdx.x] = cnt;
  __syncthreads();
  for (int off = 128; off > 0; off >>= 1) {
    if (threadIdx.x < off) sm[threadIdx.x] += sm[threadIdx.x + off];
    __syncthreads();
  }
  if (threadIdx.x == 0) flag[0] = (sm[0] > 1024) ? 1 : 0;
}

__global__ __launch_bounds__(256) void k_normalize(const void* __restrict__ eraw, int E,
                                                   const int* __restrict__ flag,
                                                   int* __restrict__ srcn,
                                                   int* __restrict__ dstn) {
  const int is64 = flag[0];
  int i = blockIdx.x * blockDim.x + threadIdx.x;
  const int stride = gridDim.x * blockDim.x;
  if (is64) {
    const long long* e = (const long long*)eraw;
    for (; i < E; i += stride) {
      srcn[i] = (int)e[i];
      dstn[i] = (int)e[(long long)E + i];
    }
  } else {
    const int* e = (const int*)eraw;
    for (; i < E; i += stride) {
      srcn[i] = e[i];
      dstn[i] = e[E + i];
    }
  }
}

__global__ __launch_bounds__(256) void k_hist(const int* __restrict__ dstn, int E,
                                              int* __restrict__ counts) {
  int i = blockIdx.x * blockDim.x + threadIdx.x;
  const int stride = gridDim.x * blockDim.x;
  for (; i < E; i += stride) atomicAdd(&counts[dstn[i]], 1);
}

__global__ __launch_bounds__(1024) void k_scan1(const int* __restrict__ counts,
                                                int* __restrict__ scanned,
                                                int* __restrict__ partials, int n) {
  __shared__ int sm[1024];
  const int i = blockIdx.x * 1024 + threadIdx.x;
  const int v = (i < n) ? counts[i] : 0;
  sm[threadIdx.x] = v;
  __syncthreads();
  for (int off = 1; off < 1024; off <<= 1) {
    int t = sm[threadIdx.x];
    int u = (threadIdx.x >= off) ? sm[threadIdx.x - off] : 0;
    __syncthreads();
    sm[threadIdx.x] = t + u;
    __syncthreads();
  }
  const int inc = sm[threadIdx.x];
  if (i < n) scanned[i] = inc - v;  // exclusive
  if (threadIdx.x == 1023) partials[blockIdx.x] = inc;
}

__global__ __launch_bounds__(1024) void k_scan2(int* __restrict__ partials, int nb) {
  __shared__ int sm[1024];
  const int v = (threadIdx.x < nb) ? partials[threadIdx.x] : 0;
  sm[threadIdx.x] = v;
  __syncthreads();
  for (int off = 1; off < 1024; off <<= 1) {
    int t = sm[threadIdx.x];
    int u = (threadIdx.x >= off) ? sm[threadIdx.x - off] : 0;
    __syncthreads();
    sm[threadIdx.x] = t + u;
    __syncthreads();
  }
  if (threadIdx.x < nb) partials[threadIdx.x] = sm[threadIdx.x] - v;  // exclusive
}

__global__ __launch_bounds__(256) void k_scan3(const int* __restrict__ scanned,
                                               const int* __restrict__ partials,
                                               const int* __restrict__ counts,
                                               int* __restrict__ offsets,
                                               int* __restrict__ cursor,
                                               float* __restrict__ dinv, int n) {
  int i = blockIdx.x * blockDim.x + threadIdx.x;
  const int stride = gridDim.x * blockDim.x;
  for (; i < n; i += stride) {
    const int o = scanned[i] + partials[i >> 10];
    offsets[i] = o;
    cursor[i] = o;
    dinv[i] = rsqrtf((float)counts[i] + 1.0f);  // +1 self-loop
  }
}

__global__ __launch_bounds__(256) void k_fill(const int* __restrict__ srcn,
                                              const int* __restrict__ dstn, int E,
                                              int* __restrict__ cursor,
                                              int* __restrict__ elist) {
  int i = blockIdx.x * blockDim.x + threadIdx.x;
  const int stride = gridDim.x * blockDim.x;
  for (; i < E; i += stride) {
    const int d = dstn[i];
    const int slot = atomicAdd(&cursor[d], 1);
    elist[slot] = srcn[i];
  }
}

__device__ __forceinline__ float f4get(const float4& v, int j) {
  return j == 0 ? v.x : (j == 1 ? v.y : (j == 2 ? v.z : v.w));
}

// h = relu?(X) @ W   (W is [F_IN, F_OUT] row-major, staged in LDS)
template <int F_IN, int F_OUT, int WPT, bool RELU_IN>
__global__ __launch_bounds__(256) void k_transform(const float* __restrict__ X,
                                                   const float* __restrict__ W,
                                                   float* __restrict__ H, int n) {
  constexpr int K4 = F_IN / 4;
  __shared__ float Ws[F_IN * F_OUT];
  for (int i = threadIdx.x; i < F_IN * F_OUT; i += blockDim.x) Ws[i] = W[i];
  __syncthreads();

  const int f = threadIdx.x % F_OUT;
  const int grp = threadIdx.x / F_OUT;
  const int grps = blockDim.x / F_OUT;
  const float4* __restrict__ X4 = reinterpret_cast<const float4*>(X);

  const long long stride = (long long)gridDim.x * grps * WPT;
  for (long long base = ((long long)blockIdx.x * grps + grp) * WPT; base < n;
       base += stride) {
    if (base + WPT <= n) {
      float acc[WPT];
      #pragma unroll
      for (int r = 0; r < WPT; ++r) acc[r] = 0.f;
      for (int k4 = 0; k4 < K4; ++k4) {
        float4 xv[WPT];
        #pragma unroll
        for (int r = 0; r < WPT; ++r) {
          xv[r] = X4[(base + r) * K4 + k4];
          if (RELU_IN) {
            xv[r].x = fmaxf(xv[r].x, 0.f);
            xv[r].y = fmaxf(xv[r].y, 0.f);
            xv[r].z = fmaxf(xv[r].z, 0.f);
            xv[r].w = fmaxf(xv[r].w, 0.f);
          }
        }
        #pragma unroll
        for (int j = 0; j < 4; ++j) {
          const float w = Ws[(k4 * 4 + j) * F_OUT + f];
          #pragma unroll
          for (int r = 0; r < WPT; ++r) acc[r] = fmaf(f4get(xv[r], j), w, acc[r]);
        }
      }
      #pragma unroll
      for (int r = 0; r < WPT; ++r) H[(base + r) * F_OUT + f] = acc[r];
    } else {
      for (int r = 0; r < WPT; ++r) {
        const long long row = base + r;
        if (row >= n) break;
        float acc = 0.f;
        for (int k = 0; k < F_IN; ++k) {
          float xv = X[row * F_IN + k];
          if (RELU_IN) xv = fmaxf(xv, 0.f);
          acc = fmaf(xv, Ws[k * F_OUT + f], acc);
        }
        H[row * F_OUT + f] = acc;
      }
    }
  }
}

// out[d] = b + dinv[d] * ( dinv[d]*H[d] + sum_{s in in(d)} dinv[s]*H[s] )
template <int F_OUT, bool RELU_OUT>
__global__ __launch_bounds__(256) void k_aggregate(const float* __restrict__ H,
                                                   const float* __restrict__ dinv,
                                                   const int* __restrict__ offsets,
                                                   const int* __restrict__ counts,
                                                   const int* __restrict__ elist,
                                                   const float* __restrict__ bias,
                                                   float* __restrict__ out, int n) {
  const int f = threadIdx.x % F_OUT;
  const int grp = threadIdx.x / F_OUT;
  const int grps = blockDim.x / F_OUT;
  const float bf = bias[f];
  for (long long d = (long long)blockIdx.x * grps + grp; d < n;
       d += (long long)gridDim.x * grps) {
    const float di = dinv[d];
    float acc = di * H[d * F_OUT + f];  // self-loop term (scaled by di below)
    const int start = offsets[d];
    const int cnt = counts[d];
    for (int j = 0; j < cnt; ++j) {
      const int s = elist[start + j];
      acc = fmaf(dinv[s], H[(long long)s * F_OUT + f], acc);
    }
    float r = fmaf(di, acc, bf);
    if (RELU_OUT) r = fmaxf(r, 0.f);
    out[d * F_OUT + f] = r;
  }
}

extern "C" void kernel_launch(void* const* d_in, const int* in_sizes, int n_in,
                              void* d_out, int out_size, void* d_ws, size_t ws_size,
                              hipStream_t stream) {
  const float* x = (const float*)d_in[0];
  const void* eraw = d_in[1];
  const float* W1 = (const float*)d_in[2];
  const float* b1 = (const float*)d_in[3];
  const float* W2 = (const float*)d_in[4];
  const float* b2 = (const float*)d_in[5];
  const float* W3 = (const float*)d_in[6];
  const float* b3 = (const float*)d_in[7];
  float* out = (float*)d_out;

  const int N = in_sizes[0] / 128;  // 100000
  const int E = in_sizes[1] / 2;    // 600000

  // ---- workspace carve (256B aligned) ----
  char* ws = (char*)d_ws;
  size_t off = 0;
  auto alloc = [&](size_t bytes) -> char* {
    char* p = ws + off;
    off = (off + bytes + 255) & ~(size_t)255;
    return p;
  };
  int*   flag     = (int*)alloc(256);
  int*   srcn     = (int*)alloc((size_t)E * 4);
  int*   dstn     = (int*)alloc((size_t)E * 4);
  int*   counts   = (int*)alloc((size_t)N * 4);
  int*   scanned  = (int*)alloc((size_t)N * 4);
  int*   partials = (int*)alloc(1024 * 4);
  int*   offsets  = (int*)alloc((size_t)N * 4);
  int*   cursor   = (int*)alloc((size_t)N * 4);
  int*   elist    = (int*)alloc((size_t)E * 4);
  float* dinv     = (float*)alloc((size_t)N * 4);
  float* hbuf     = (float*)alloc((size_t)N * 64 * 4);
  float* obuf     = (float*)alloc((size_t)N * 64 * 4);
  (void)ws_size; (void)n_in; (void)out_size;

  // ---- CSR build (per call; deterministic structure) ----
  hipMemsetAsync(counts, 0, (size_t)N * 4, stream);
  k_detect<<<1, 256, 0, stream>>>((const unsigned int*)eraw, flag);
  k_normalize<<<FULL_GRID, 256, 0, stream>>>(eraw, E, flag, srcn, dstn);
  k_hist<<<FULL_GRID, 256, 0, stream>>>(dstn, E, counts);
  const int NB = (N + 1023) >> 10;
  k_scan1<<<NB, 1024, 0, stream>>>(counts, scanned, partials, N);
  k_scan2<<<1, 1024, 0, stream>>>(partials, NB);
  k_scan3<<<(N + 255) / 256, 256, 0, stream>>>(scanned, partials, counts, offsets,
                                               cursor, dinv, N);
  k_fill<<<FULL_GRID, 256, 0, stream>>>(srcn, dstn, E, cursor, elist);

  // ---- layer 1: 128 -> 64 ----
  k_transform<128, 64, 4, false><<<FULL_GRID, 256, 0, stream>>>(x, W1, hbuf, N);
  k_aggregate<64, false><<<FULL_GRID, 256, 0, stream>>>(hbuf, dinv, offsets, counts,
                                                        elist, b1, obuf, N);
  // ---- layer 2: 64 -> 32 (ReLU on input) ----
  k_transform<64, 32, 4, true><<<FULL_GRID, 256, 0, stream>>>(obuf, W2, hbuf, N);
  k_aggregate<32, false><<<FULL_GRID, 256, 0, stream>>>(hbuf, dinv, offsets, counts,
                                                        elist, b2, obuf, N);
  // ---- layer 3: 32 -> 2 (ReLU on input, ReLU on output) ----
  k_transform<32, 2, 4, true><<<FULL_GRID, 256, 0, stream>>>(obuf, W3, hbuf, N);
  k_aggregate<2, true><<<FULL_GRID, 256, 0, stream>>>(hbuf, dinv, offsets, counts,
                                                      elist, b3, out, N);
}

// Round 2
// 214.136 us; speedup vs baseline: 1.5861x; 1.5861x over previous
//
#include <hip/hip_runtime.h>
#include <math.h>

// ---------------------------------------------------------------------------
// GCNEncoder: 3 stacked GCNConv layers (symmetric norm, self-loops) + ReLU.
//   - edge dtype auto-detect (int64 vs int32), normalize+histogram fused.
//   - dst-CSR per call: histogram -> 2-level scan -> fill.
//   - transform: LDS-tiled register-blocked fp32 GEMM (4x4 thread tile),
//     epilogue pre-scales by dinv:  hs = dinv .* (X @ W)
//   - aggregate: out[d] = relu(b + dinv[d]*(hs[d] + sum_{s in(d)} hs[s]))
//     gather-style, lane = feature, 4 edges in flight.
//   - layer-3 transform (32->2) fused into layer-2 aggregate epilogue via
//     32-lane shuffle reduction (out2 never materialized).
// ---------------------------------------------------------------------------

#define FULL_GRID 2048

__global__ __launch_bounds__(256) void k_detect(const unsigned int* __restrict__ words,
                                                int* __restrict__ flag) {
  __shared__ int sm[256];
  int cnt = 0;
  #pragma unroll
  for (int j = 0; j < 8; ++j) {
    int idx = (threadIdx.x * 8 + j) * 2 + 1;  // odd words of first 4096 words
    cnt += (words[idx] == 0u) ? 1 : 0;
  }
  sm[threadIdx.x] = cnt;
  __syncthreads();
  for (int off = 128; off > 0; off >>= 1) {
    if (threadIdx.x < off) sm[threadIdx.x] += sm[threadIdx.x + off];
    __syncthreads();
  }
  if (threadIdx.x == 0) flag[0] = (sm[0] > 1024) ? 1 : 0;
}

// normalize edge dtype + destination histogram in one pass
__global__ __launch_bounds__(256) void k_normalize_hist(const void* __restrict__ eraw, int E,
                                                        const int* __restrict__ flag,
                                                        int* __restrict__ srcn,
                                                        int* __restrict__ dstn,
                                                        int* __restrict__ counts) {
  const int is64 = flag[0];
  int i = blockIdx.x * blockDim.x + threadIdx.x;
  const int stride = gridDim.x * blockDim.x;
  if (is64) {
    const long long* e = (const long long*)eraw;
    for (; i < E; i += stride) {
      const int s = (int)e[i];
      const int d = (int)e[(long long)E + i];
      srcn[i] = s;
      dstn[i] = d;
      atomicAdd(&counts[d], 1);
    }
  } else {
    const int* e = (const int*)eraw;
    for (; i < E; i += stride) {
      const int s = e[i];
      const int d = e[E + i];
      srcn[i] = s;
      dstn[i] = d;
      atomicAdd(&counts[d], 1);
    }
  }
}

__global__ __launch_bounds__(1024) void k_scan1(const int* __restrict__ counts,
                                                int* __restrict__ scanned,
                                                int* __restrict__ partials, int n) {
  __shared__ int sm[1024];
  const int i = blockIdx.x * 1024 + threadIdx.x;
  const int v = (i < n) ? counts[i] : 0;
  sm[threadIdx.x] = v;
  __syncthreads();
  for (int off = 1; off < 1024; off <<= 1) {
    int t = sm[threadIdx.x];
    int u = (threadIdx.x >= off) ? sm[threadIdx.x - off] : 0;
    __syncthreads();
    sm[threadIdx.x] = t + u;
    __syncthreads();
  }
  const int inc = sm[threadIdx.x];
  if (i < n) scanned[i] = inc - v;  // exclusive
  if (threadIdx.x == 1023) partials[blockIdx.x] = inc;
}

__global__ __launch_bounds__(1024) void k_scan2(int* __restrict__ partials, int nb) {
  __shared__ int sm[1024];
  const int v = (threadIdx.x < nb) ? partials[threadIdx.x] : 0;
  sm[threadIdx.x] = v;
  __syncthreads();
  for (int off = 1; off < 1024; off <<= 1) {
    int t = sm[threadIdx.x];
    int u = (threadIdx.x >= off) ? sm[threadIdx.x - off] : 0;
    __syncthreads();
    sm[threadIdx.x] = t + u;
    __syncthreads();
  }
  if (threadIdx.x < nb) partials[threadIdx.x] = sm[threadIdx.x] - v;  // exclusive
}

__global__ __launch_bounds__(256) void k_scan3(const int* __restrict__ scanned,
                                               const int* __restrict__ partials,
                                               const int* __restrict__ counts,
                                               int* __restrict__ offsets,
                                               int* __restrict__ cursor,
                                               float* __restrict__ dinv, int n) {
  int i = blockIdx.x * blockDim.x + threadIdx.x;
  const int stride = gridDim.x * blockDim.x;
  for (; i < n; i += stride) {
    const int o = scanned[i] + partials[i >> 10];
    offsets[i] = o;
    cursor[i] = o;
    dinv[i] = rsqrtf((float)counts[i] + 1.0f);  // +1 self-loop
  }
}

__global__ __launch_bounds__(256) void k_fill(const int* __restrict__ srcn,
                                              const int* __restrict__ dstn, int E,
                                              int* __restrict__ cursor,
                                              int* __restrict__ elist) {
  int i = blockIdx.x * blockDim.x + threadIdx.x;
  const int stride = gridDim.x * blockDim.x;
  for (; i < E; i += stride) {
    const int d = dstn[i];
    const int slot = atomicAdd(&cursor[d], 1);
    elist[slot] = srcn[i];
  }
}

// hs = dinv .* (X @ W)   (register-tiled GEMM, X tile + W chunk in LDS)
// thread tile 4 rows x 4 cols; rows strided by ROWT for conflict-free LDS reads.
template <int F_IN, int F_OUT, int TILE_M>
__global__ __launch_bounds__(256) void k_transform(const float* __restrict__ X,
                                                   const float* __restrict__ W,
                                                   const float* __restrict__ dinv,
                                                   float* __restrict__ H, int n) {
  constexpr int TN = 4;
  constexpr int COLT = F_OUT / TN;       // col-threads
  constexpr int ROWT = 256 / COLT;       // row-threads
  constexpr int TM = TILE_M / ROWT;      // rows per thread
  constexpr int KC = (F_IN > 64) ? 64 : F_IN;
  constexpr int NKC = F_IN / KC;
  constexpr int XP = F_IN + 4;           // padded row pitch (floats), 16B aligned
  static_assert(TM * ROWT == TILE_M && COLT * TN == F_OUT, "tiling");

  __shared__ float Xs[TILE_M * XP];
  __shared__ float Ws[KC * F_OUT];
  __shared__ float Ds[TILE_M];

  const int tid = threadIdx.x;
  const long long base = (long long)blockIdx.x * TILE_M;

  {  // stage X tile (zero-fill tail) + dinv
    const float4* __restrict__ X4 = (const float4*)X;
    constexpr int C4 = F_IN / 4;
    for (int g = tid; g < TILE_M * C4; g += 256) {
      const int row = g / C4, c4 = g % C4;
      float4 v = make_float4(0.f, 0.f, 0.f, 0.f);
      if (base + row < n) v = X4[(base + row) * C4 + c4];
      *(float4*)&Xs[row * XP + c4 * 4] = v;
    }
    for (int r = tid; r < TILE_M; r += 256)
      Ds[r] = (base + r < n) ? dinv[base + r] : 0.f;
  }

  const int ct = tid % COLT;
  const int rt = tid / COLT;

  float4 acc[TM];
  #pragma unroll
  for (int r = 0; r < TM; ++r) acc[r] = make_float4(0.f, 0.f, 0.f, 0.f);

  const float4* __restrict__ W4 = (const float4*)W;
  float4* Ws4s = (float4*)Ws;
  const float4* Xs4 = (const float4*)Xs;
  const float4* Ws4 = (const float4*)Ws;

  for (int kc = 0; kc < NKC; ++kc) {
    __syncthreads();  // Xs ready / previous chunk consumed
    constexpr int WC4 = KC * F_OUT / 4;
    for (int i = tid; i < WC4; i += 256) Ws4s[i] = W4[kc * WC4 + i];
    __syncthreads();
    #pragma unroll
    for (int k4 = 0; k4 < KC / 4; ++k4) {
      const float4 wv0 = Ws4[(k4 * 4 + 0) * (F_OUT / 4) + ct];
      const float4 wv1 = Ws4[(k4 * 4 + 1) * (F_OUT / 4) + ct];
      const float4 wv2 = Ws4[(k4 * 4 + 2) * (F_OUT / 4) + ct];
      const float4 wv3 = Ws4[(k4 * 4 + 3) * (F_OUT / 4) + ct];
      #pragma unroll
      for (int r = 0; r < TM; ++r) {
        const float4 xv = Xs4[(rt + r * ROWT) * (XP / 4) + kc * (KC / 4) + k4];
        acc[r].x = fmaf(xv.x, wv0.x, acc[r].x);
        acc[r].y = fmaf(xv.x, wv0.y, acc[r].y);
        acc[r].z = fmaf(xv.x, wv0.z, acc[r].z);
        acc[r].w = fmaf(xv.x, wv0.w, acc[r].w);
        acc[r].x = fmaf(xv.y, wv1.x, acc[r].x);
        acc[r].y = fmaf(xv.y, wv1.y, acc[r].y);
        acc[r].z = fmaf(xv.y, wv1.z, acc[r].z);
        acc[r].w = fmaf(xv.y, wv1.w, acc[r].w);
        acc[r].x = fmaf(xv.z, wv2.x, acc[r].x);
        acc[r].y = fmaf(xv.z, wv2.y, acc[r].y);
        acc[r].z = fmaf(xv.z, wv2.z, acc[r].z);
        acc[r].w = fmaf(xv.z, wv2.w, acc[r].w);
        acc[r].x = fmaf(xv.w, wv3.x, acc[r].x);
        acc[r].y = fmaf(xv.w, wv3.y, acc[r].y);
        acc[r].z = fmaf(xv.w, wv3.z, acc[r].z);
        acc[r].w = fmaf(xv.w, wv3.w, acc[r].w);
      }
    }
  }

  #pragma unroll
  for (int r = 0; r < TM; ++r) {
    const int row = rt + r * ROWT;
    if (base + row < n) {
      const float di = Ds[row];
      float4 v = acc[r];
      v.x *= di; v.y *= di; v.z *= di; v.w *= di;
      *(float4*)&H[(base + row) * F_OUT + ct * 4] = v;
    }
  }
}

// out[d][f] = relu(b[f] + dinv[d]*(hs[d][f] + sum_s hs[s][f]))
// FUSE_W3: additionally h3 = relu(out2) @ W3, write hs3 = dinv*h3 (F_OUT=2).
template <int F, bool RELU_OUT, bool FUSE_W3>
__global__ __launch_bounds__(256) void k_aggregate(const float* __restrict__ HS,
                                                   const float* __restrict__ dinv,
                                                   const int* __restrict__ offsets,
                                                   const int* __restrict__ counts,
                                                   const int* __restrict__ elist,
                                                   const float* __restrict__ bias,
                                                   const float* __restrict__ W3,
                                                   float* __restrict__ out, int n) {
  const int f = threadIdx.x % F;
  const int grp = threadIdx.x / F;
  constexpr int GRPS = 256 / F;
  const float bf = bias[f];
  float w30 = 0.f, w31 = 0.f;
  if (FUSE_W3) { w30 = W3[f * 2 + 0]; w31 = W3[f * 2 + 1]; }

  for (long long d = (long long)blockIdx.x * GRPS + grp; d < n;
       d += (long long)gridDim.x * GRPS) {
    const float di = dinv[d];
    float acc = HS[d * F + f];  // self-loop (already dinv[d]-scaled)
    const int start = offsets[d];
    const int cnt = counts[d];
    int j = 0;
    for (; j + 4 <= cnt; j += 4) {
      const int s0 = elist[start + j + 0];
      const int s1 = elist[start + j + 1];
      const int s2 = elist[start + j + 2];
      const int s3 = elist[start + j + 3];
      const float v0 = HS[(long long)s0 * F + f];
      const float v1 = HS[(long long)s1 * F + f];
      const float v2 = HS[(long long)s2 * F + f];
      const float v3 = HS[(long long)s3 * F + f];
      acc += (v0 + v1) + (v2 + v3);
    }
    for (; j < cnt; ++j) acc += HS[(long long)elist[start + j] * F + f];

    float r = fmaf(di, acc, bf);
    if (RELU_OUT) r = fmaxf(r, 0.f);
    if (!FUSE_W3) {
      out[d * F + f] = r;
    } else {
      float t0 = r * w30, t1 = r * w31;
      #pragma unroll
      for (int m = 1; m < 32; m <<= 1) {
        t0 += __shfl_xor(t0, m, 64);
        t1 += __shfl_xor(t1, m, 64);
      }
      if (f == 0) {
        out[d * 2 + 0] = di * t0;
        out[d * 2 + 1] = di * t1;
      }
    }
  }
}

extern "C" void kernel_launch(void* const* d_in, const int* in_sizes, int n_in,
                              void* d_out, int out_size, void* d_ws, size_t ws_size,
                              hipStream_t stream) {
  const float* x = (const float*)d_in[0];
  const void* eraw = d_in[1];
  const float* W1 = (const float*)d_in[2];
  const float* b1 = (const float*)d_in[3];
  const float* W2 = (const float*)d_in[4];
  const float* b2 = (const float*)d_in[5];
  const float* W3 = (const float*)d_in[6];
  const float* b3 = (const float*)d_in[7];
  float* out = (float*)d_out;

  const int N = in_sizes[0] / 128;  // 100000
  const int E = in_sizes[1] / 2;    // 600000

  char* ws = (char*)d_ws;
  size_t off = 0;
  auto alloc = [&](size_t bytes) -> char* {
    char* p = ws + off;
    off = (off + bytes + 255) & ~(size_t)255;
    return p;
  };
  int*   flag     = (int*)alloc(256);
  int*   srcn     = (int*)alloc((size_t)E * 4);
  int*   dstn     = (int*)alloc((size_t)E * 4);
  int*   counts   = (int*)alloc((size_t)N * 4);
  int*   scanned  = (int*)alloc((size_t)N * 4);
  int*   partials = (int*)alloc(1024 * 4);
  int*   offsets  = (int*)alloc((size_t)N * 4);
  int*   cursor   = (int*)alloc((size_t)N * 4);
  int*   elist    = (int*)alloc((size_t)E * 4);
  float* dinv     = (float*)alloc((size_t)N * 4);
  float* hbuf     = (float*)alloc((size_t)N * 64 * 4);  // hs1 [N,64] then hs2 [N,32]
  float* obuf     = (float*)alloc((size_t)N * 64 * 4);  // out1 [N,64] then hs3 [N,2]
  (void)ws_size; (void)n_in; (void)out_size;

  // ---- CSR build ----
  hipMemsetAsync(counts, 0, (size_t)N * 4, stream);
  k_detect<<<1, 256, 0, stream>>>((const unsigned int*)eraw, flag);
  k_normalize_hist<<<FULL_GRID, 256, 0, stream>>>(eraw, E, flag, srcn, dstn, counts);
  const int NB = (N + 1023) >> 10;
  k_scan1<<<NB, 1024, 0, stream>>>(counts, scanned, partials, N);
  k_scan2<<<1, 1024, 0, stream>>>(partials, NB);
  k_scan3<<<(N + 255) / 256, 256, 0, stream>>>(scanned, partials, counts, offsets,
                                               cursor, dinv, N);
  k_fill<<<FULL_GRID, 256, 0, stream>>>(srcn, dstn, E, cursor, elist);

  // ---- layer 1: transform 128->64 (hs1 = dinv.*(x@W1)), aggregate+ReLU ----
  k_transform<128, 64, 64><<<(N + 63) / 64, 256, 0, stream>>>(x, W1, dinv, hbuf, N);
  k_aggregate<64, true, false><<<(N + 3) / 4, 256, 0, stream>>>(
      hbuf, dinv, offsets, counts, elist, b1, nullptr, obuf, N);

  // ---- layer 2: transform 64->32 (hs2), aggregate+ReLU + fused W3 (hs3) ----
  k_transform<64, 32, 128><<<(N + 127) / 128, 256, 0, stream>>>(obuf, W2, dinv, hbuf, N);
  k_aggregate<32, true, true><<<(N + 7) / 8, 256, 0, stream>>>(
      hbuf, dinv, offsets, counts, elist, b2, W3, obuf, N);

  // ---- layer 3: aggregate hs3 + ReLU -> out ----
  k_aggregate<2, true, false><<<(N + 127) / 128, 256, 0, stream>>>(
      obuf, dinv, offsets, counts, elist, b3, nullptr, out, N);
}